// Round 8
// baseline (325.200 us; speedup 1.0000x reference)
//
#include <hip/hip_runtime.h>

// Problem constants
#define LQ  512
#define LKN 512
#define BB  32
#define DD  768
#define QT  32                // q rows per block (2 x 16-row MFMA tiles)
#define DSL (DD / 4)          // 192: d-slice per wave (PV phase)

typedef float    f4     __attribute__((ext_vector_type(4)));
typedef _Float16 half8  __attribute__((ext_vector_type(8)));
typedef _Float16 half4  __attribute__((ext_vector_type(4)));
typedef __fp16   fp16x2 __attribute__((ext_vector_type(2)));

union H8 { half8 h; unsigned int u[4]; };

__device__ __forceinline__ unsigned int pk2(float a, float b) {
    union { fp16x2 h; unsigned int u; } c;
    c.h = __builtin_amdgcn_cvt_pkrtz(a, b);
    return c.u;
}

__device__ __forceinline__ half8 cvt8(f4 a, f4 b) {
    H8 r;
    r.u[0] = pk2(a[0], a[1]); r.u[1] = pk2(a[2], a[3]);
    r.u[2] = pk2(b[0], b[1]); r.u[3] = pk2(b[2], b[3]);
    return r.h;
}

// ---------------------------------------------------------------------------
// Prep: per 64x64 (l,d) tile of one (side,b), via LDS tile T:
//  - XF: MFMA-fragment-packed f16  (serves Q A-frags and K B-frags)
//  - XT: transposed f16 [B][D][L]  (V B-frags in PV)
// ---------------------------------------------------------------------------
__global__ __launch_bounds__(256)
void prep_cvt_t(const float* __restrict__ x1, const float* __restrict__ x2,
                _Float16* __restrict__ xf1, _Float16* __restrict__ xf2,
                _Float16* __restrict__ xt1, _Float16* __restrict__ xt2)
{
    const int bi   = blockIdx.x;            // 2*32*8*12 = 6144
    const int side = bi / 3072;
    const int rem  = bi % 3072;
    const int b    = rem / 96;
    const int rem2 = rem % 96;
    const int l0   = (rem2 / 12) * 64;
    const int d0   = (rem2 % 12) * 64;

    const float* __restrict__ X  = side ? x2  : x1;
    _Float16* __restrict__    XF = side ? xf2 : xf1;
    _Float16* __restrict__    XT = side ? xt2 : xt1;

    __shared__ _Float16 T[64][72];          // padded

    const int tid = threadIdx.x;
    {
        const int r  = tid >> 4;
        const int c4 = (tid & 15) * 4;
        for (int rr = r; rr < 64; rr += 16) {
            const size_t idx = ((size_t)(l0 + rr) * BB + b) * DD + d0 + c4;
            f4 v = *(const f4*)(X + idx);
            half4 h;
            h[0] = (_Float16)v[0]; h[1] = (_Float16)v[1];
            h[2] = (_Float16)v[2]; h[3] = (_Float16)v[3];
            *(half4*)&T[rr][c4] = h;
        }
    }
    __syncthreads();
    {
        const int d  = tid >> 2;
        const int lq = (tid & 3) * 16;
        half8 a, c;
        #pragma unroll
        for (int i = 0; i < 8; ++i) { a[i] = T[lq + i][d]; c[i] = T[lq + 8 + i][d]; }
        _Float16* p = XT + ((size_t)b * DD + d0 + d) * LKN + l0 + lq;
        *(half8*)p       = a;
        *(half8*)(p + 8) = c;
    }
    #pragma unroll
    for (int c = tid; c < 512; c += 256) {
        const int t16l = c >> 7;
        const int ksl  = (c >> 6) & 1;
        const int ln   = c & 63;
        const int lr_  = ln & 15;
        const int lg_  = ln >> 4;
        half8 v = *(const half8*)&T[t16l * 16 + lr_][ksl * 32 + lg_ * 8];
        const size_t t16g = (size_t)(l0 >> 4) + t16l;
        const size_t ksg  = (size_t)(d0 >> 5) + ksl;
        *(half8*)(XF + (((size_t)b * 32 + t16g) * 24 + ksg) * 512 + ln * 8) = v;
    }
}

// ---------------------------------------------------------------------------
// Flash v5 — phase-separated, QT=32 (halves L2/L3 traffic vs QT=16).
// Per block: 32 q-rows of one (side,b). 4 waves.
// Phase 1: wave w computes S[32][128] (k-cols w*128..+127) over full D.
// Phase 2: row stats + P(f16) -> LDS (XOR-swizzled).
// Phase 3: wave w computes O[32][192-d-slice] over all 512 k.
// ---------------------------------------------------------------------------
__global__ __launch_bounds__(256)
void coatt_flash_f16(const _Float16* __restrict__ xf1, const _Float16* __restrict__ xf2,
                     const _Float16* __restrict__ xt1, const _Float16* __restrict__ xt2,
                     const float* __restrict__ m1, const float* __restrict__ m2,
                     float* __restrict__ o1, float* __restrict__ o2)
{
    const int i    = blockIdx.x;          // 0..1023
    const int xcd  = i & 7;
    const int j    = i >> 3;              // 0..127
    const int qt   = j & 15;              // 16 q-tiles of 32 rows
    const int slot = j >> 4;              // 0..7
    const int side = slot & 1;            // both sides of same b share an XCD
    const int b    = xcd * 4 + (slot >> 1);

    const _Float16* __restrict__ QF = side ? xf2 : xf1;
    const _Float16* __restrict__ KF = side ? xf1 : xf2;
    const _Float16* __restrict__ VT = side ? xt1 : xt2;
    const float* __restrict__    MK = side ? m1  : m2;
    float* __restrict__         OUT = side ? o2  : o1;

    const int tid  = threadIdx.x;
    const int lane = tid & 63;
    const int w    = tid >> 6;    // wave: phase1 k-slice / phase3 d-slice
    const int lr   = lane & 15;
    const int lg   = lane >> 4;

    const int q0 = qt * QT;

    __shared__ _Float16 plds_h[QT * LKN];   // 32 KB; byte = row*1024 + (col*2 ^ ((row&7)<<4))
    __shared__ float redmax[4][QT];
    __shared__ float redsum[4][QT];
    __shared__ float mask_s[LKN];
    char* const pb = (char*)plds_h;

    for (int t = tid; t < LKN; t += 256) mask_s[t] = MK[t * BB + b];

    // ---------------- Phase 1: S = Q.K^T for this wave's 128 k-cols ----------
    f4 sacc[16];                 // [qq*8 + kt]
    #pragma unroll
    for (int t = 0; t < 16; ++t) sacc[t] = f4{0.f, 0.f, 0.f, 0.f};

    {
        const _Float16* qbase = QF + (((size_t)b * 32 + qt * 2) * 24) * 512 + lane * 8;
        const _Float16* kbase = KF + (((size_t)b * 32 + w * 8) * 24) * 512 + lane * 8;
        __builtin_amdgcn_s_setprio(1);
        #pragma unroll
        for (int ks = 0; ks < 24; ++ks) {
            const half8 q0f = *(const half8*)(qbase + ks * 512);
            const half8 q1f = *(const half8*)(qbase + (24 + ks) * 512);
            #pragma unroll
            for (int kt = 0; kt < 8; ++kt) {
                const half8 kf = *(const half8*)(kbase + ((size_t)kt * 24 + ks) * 512);
                sacc[kt]     = __builtin_amdgcn_mfma_f32_16x16x32_f16(q0f, kf, sacc[kt], 0, 0, 0);
                sacc[8 + kt] = __builtin_amdgcn_mfma_f32_16x16x32_f16(q1f, kf, sacc[8 + kt], 0, 0, 0);
            }
        }
        __builtin_amdgcn_s_setprio(0);
    }

    // ---------------- Phase 2: softmax stats + P -> LDS ----------------------
    // lane holds rows: row = qq*16 + 4*lg + r ; cols: w*128 + kt*16 + lr
    float rm0[4], rm1[4];
    #pragma unroll
    for (int r = 0; r < 4; ++r) {
        rm0[r] = fmaxf(fmaxf(fmaxf(sacc[0][r], sacc[1][r]), fmaxf(sacc[2][r], sacc[3][r])),
                       fmaxf(fmaxf(sacc[4][r], sacc[5][r]), fmaxf(sacc[6][r], sacc[7][r])));
        rm1[r] = fmaxf(fmaxf(fmaxf(sacc[8][r], sacc[9][r]), fmaxf(sacc[10][r], sacc[11][r])),
                       fmaxf(fmaxf(sacc[12][r], sacc[13][r]), fmaxf(sacc[14][r], sacc[15][r])));
    }
    #pragma unroll
    for (int d = 1; d <= 8; d <<= 1) {
        #pragma unroll
        for (int r = 0; r < 4; ++r) {
            rm0[r] = fmaxf(rm0[r], __shfl_xor(rm0[r], d));
            rm1[r] = fmaxf(rm1[r], __shfl_xor(rm1[r], d));
        }
    }
    if (lr < 8) {
        const int qq = lr >> 2, r = lr & 3;
        const float v0 = (r == 0) ? rm0[0] : (r == 1) ? rm0[1] : (r == 2) ? rm0[2] : rm0[3];
        const float v1 = (r == 0) ? rm1[0] : (r == 1) ? rm1[1] : (r == 2) ? rm1[2] : rm1[3];
        redmax[w][(qq << 4) + 4 * lg + r] = qq ? v1 : v0;
    }
    __syncthreads();   // [B1] redmax + mask_s visible

    float M0[4], M1[4];
    #pragma unroll
    for (int r = 0; r < 4; ++r) {
        M0[r] = fmaxf(fmaxf(redmax[0][4 * lg + r], redmax[1][4 * lg + r]),
                      fmaxf(redmax[2][4 * lg + r], redmax[3][4 * lg + r]));
        M1[r] = fmaxf(fmaxf(redmax[0][16 + 4 * lg + r], redmax[1][16 + 4 * lg + r]),
                      fmaxf(redmax[2][16 + 4 * lg + r], redmax[3][16 + 4 * lg + r]));
    }

    float mval[8];
    #pragma unroll
    for (int kt = 0; kt < 8; ++kt) mval[kt] = mask_s[w * 128 + kt * 16 + lr];

    float ps0[4] = {0.f, 0.f, 0.f, 0.f}, ps1[4] = {0.f, 0.f, 0.f, 0.f};
    #pragma unroll
    for (int kt = 0; kt < 8; ++kt) {
        #pragma unroll
        for (int r = 0; r < 4; ++r) {
            const int row0 = 4 * lg + r;
            const int colb = (w * 128 + kt * 16 + lr) * 2;
            const int by0  = row0 * 1024 + (colb ^ ((row0 & 7) << 4));
            const float p0 = __expf(sacc[kt][r] - M0[r]) * mval[kt];
            ps0[r] += p0;
            *(_Float16*)(pb + by0) = (_Float16)p0;
            const float p1 = __expf(sacc[8 + kt][r] - M1[r]) * mval[kt];
            ps1[r] += p1;
            *(_Float16*)(pb + by0 + 16384) = (_Float16)p1;   // row+16, same swizzle
        }
    }
    #pragma unroll
    for (int d = 1; d <= 8; d <<= 1) {
        #pragma unroll
        for (int r = 0; r < 4; ++r) {
            ps0[r] += __shfl_xor(ps0[r], d);
            ps1[r] += __shfl_xor(ps1[r], d);
        }
    }
    if (lr < 8) {
        const int qq = lr >> 2, r = lr & 3;
        const float v0 = (r == 0) ? ps0[0] : (r == 1) ? ps0[1] : (r == 2) ? ps0[2] : ps0[3];
        const float v1 = (r == 0) ? ps1[0] : (r == 1) ? ps1[1] : (r == 2) ? ps1[2] : ps1[3];
        redsum[w][(qq << 4) + 4 * lg + r] = qq ? v1 : v0;
    }
    __syncthreads();   // [B2] redsum + P tile visible

    float il0[4], il1[4];
    #pragma unroll
    for (int r = 0; r < 4; ++r) {
        const float L0 = redsum[0][4 * lg + r] + redsum[1][4 * lg + r]
                       + redsum[2][4 * lg + r] + redsum[3][4 * lg + r];
        const float L1 = redsum[0][16 + 4 * lg + r] + redsum[1][16 + 4 * lg + r]
                       + redsum[2][16 + 4 * lg + r] + redsum[3][16 + 4 * lg + r];
        il0[r] = 1.f / (L0 + 1e-8f);
        il1[r] = 1.f / (L1 + 1e-8f);
    }

    // ---------------- Phase 3: O = P.V for this wave's 192 d-slice -----------
    const int d0 = w * DSL;
    f4 acc[24];                  // [qq*12 + nt]
    #pragma unroll
    for (int t = 0; t < 24; ++t) acc[t] = f4{0.f, 0.f, 0.f, 0.f};

    {
        const _Float16* vtb = VT + ((size_t)b * DD + d0 + lr) * LKN + lg * 8;
        __builtin_amdgcn_s_setprio(1);
        #pragma unroll
        for (int ks2 = 0; ks2 < 16; ++ks2) {
            const int pbyte = (ks2 * 64 + lg * 16) ^ ((lr & 7) << 4);
            const half8 pa0 = *(const half8*)(pb + lr * 1024 + pbyte);
            const half8 pa1 = *(const half8*)(pb + (16 + lr) * 1024 + pbyte);
            #pragma unroll
            for (int nt = 0; nt < 12; ++nt) {
                const half8 vf = *(const half8*)(vtb + (size_t)nt * 16 * LKN + ks2 * 32);
                acc[nt]      = __builtin_amdgcn_mfma_f32_16x16x32_f16(pa0, vf, acc[nt], 0, 0, 0);
                acc[12 + nt] = __builtin_amdgcn_mfma_f32_16x16x32_f16(pa1, vf, acc[12 + nt], 0, 0, 0);
            }
        }
        __builtin_amdgcn_s_setprio(0);
    }

    // ---------------- Epilogue ----------------------------------------------
    #pragma unroll
    for (int nt = 0; nt < 12; ++nt) {
        #pragma unroll
        for (int r = 0; r < 4; ++r) {
            const size_t base = (size_t)(q0 + 4 * lg + r) * BB + b;
            OUT[base * DD + d0 + nt * 16 + lr]                       = acc[nt][r] * il0[r];
            OUT[(base + (size_t)16 * BB) * DD + d0 + nt * 16 + lr]   = acc[12 + nt][r] * il1[r];
        }
    }
}

// ---------------------------------------------------------------------------
// Fallback (f32 direct) — used only if ws too small.
// ---------------------------------------------------------------------------
__global__ __launch_bounds__(256)
void coatt_flash_f32(const float* __restrict__ x1, const float* __restrict__ m1,
                     const float* __restrict__ x2, const float* __restrict__ m2,
                     float* __restrict__ o1, float* __restrict__ o2)
{
    const int i    = blockIdx.x;
    const int xcd  = i & 7;
    const int j    = i >> 3;
    const int pair = xcd * 8 + (j >> 5);
    const int qt   = j & 31;
    const int side = pair >> 5;
    const int b    = pair & 31;

    const float* __restrict__ Q   = side ? x2 : x1;
    const float* __restrict__ K   = side ? x1 : x2;
    const float* __restrict__ MK  = side ? m1 : m2;
    float* __restrict__       OUT = side ? o2 : o1;

    const int tid  = threadIdx.x;
    const int lane = tid & 63;
    const int w    = tid >> 6;
    const int lr   = lane & 15;
    const int lg   = lane >> 4;

    const int q0 = qt * 16;
    const int d0 = w * DSL;

    __shared__ float sred[4][16][36];
    __shared__ float mask_s[LKN];

    for (int t = tid; t < LKN; t += 256) mask_s[t] = MK[t * BB + b];

    half8 qf[6];
    {
        const float* qrow = Q + ((q0 + lr) * BB + b) * DD + d0 + lg * 8;
        #pragma unroll
        for (int ks = 0; ks < 6; ++ks) {
            f4 a = *(const f4*)(qrow + ks * 32);
            f4 c = *(const f4*)(qrow + ks * 32 + 4);
            qf[ks] = cvt8(a, c);
        }
    }

    f4 acc[12];
    #pragma unroll
    for (int t = 0; t < 12; ++t) acc[t] = f4{0.f, 0.f, 0.f, 0.f};
    float Mrun = -3.0e38f, Lrun = 0.f;

    for (int kt = 0; kt < 16; ++kt) {
        const int k0 = kt * 32;
        f4 s0 = {0.f,0.f,0.f,0.f}, s1 = {0.f,0.f,0.f,0.f};
        {
            const float* kb0 = K + ((k0 + lr) * BB + b) * DD + d0 + lg * 8;
            const float* kb1 = kb0 + 16 * BB * DD;
            #pragma unroll
            for (int ks = 0; ks < 6; ++ks) {
                f4 a0 = *(const f4*)(kb0 + ks * 32);
                f4 c0 = *(const f4*)(kb0 + ks * 32 + 4);
                s0 = __builtin_amdgcn_mfma_f32_16x16x32_f16(qf[ks], cvt8(a0, c0), s0, 0, 0, 0);
                f4 a1 = *(const f4*)(kb1 + ks * 32);
                f4 c1 = *(const f4*)(kb1 + ks * 32 + 4);
                s1 = __builtin_amdgcn_mfma_f32_16x16x32_f16(qf[ks], cvt8(a1, c1), s1, 0, 0, 0);
            }
        }
        __syncthreads();
        #pragma unroll
        for (int r = 0; r < 4; ++r) {
            sred[w][4 * lg + r][lr]      = s0[r];
            sred[w][4 * lg + r][16 + lr] = s1[r];
        }
        __syncthreads();
        f4 sa = {0.f,0.f,0.f,0.f}, sb = {0.f,0.f,0.f,0.f};
        #pragma unroll
        for (int ww = 0; ww < 4; ++ww) {
            sa += *(const f4*)&sred[ww][lr][lg * 8];
            sb += *(const f4*)&sred[ww][lr][lg * 8 + 4];
        }
        float tmax = fmaxf(fmaxf(fmaxf(sa[0], sa[1]), fmaxf(sa[2], sa[3])),
                           fmaxf(fmaxf(sb[0], sb[1]), fmaxf(sb[2], sb[3])));
        tmax = fmaxf(tmax, __shfl_xor(tmax, 16));
        tmax = fmaxf(tmax, __shfl_xor(tmax, 32));
        const float Mnew  = fmaxf(Mrun, tmax);
        const float scale = __expf(Mrun - Mnew);
        float p[8];
        float psum = 0.f;
        const float* mrow = &mask_s[k0 + lg * 8];
        #pragma unroll
        for (int t = 0; t < 4; ++t) { p[t]     = __expf(sa[t] - Mnew) * mrow[t];     psum += p[t]; }
        #pragma unroll
        for (int t = 0; t < 4; ++t) { p[4 + t] = __expf(sb[t] - Mnew) * mrow[4 + t]; psum += p[4 + t]; }
        psum += __shfl_xor(psum, 16);
        psum += __shfl_xor(psum, 32);
        Lrun = Lrun * scale + psum;
        Mrun = Mnew;

        H8 pf;
        pf.u[0] = pk2(p[0], p[1]); pf.u[1] = pk2(p[2], p[3]);
        pf.u[2] = pk2(p[4], p[5]); pf.u[3] = pk2(p[6], p[7]);

        float sc[4];
        #pragma unroll
        for (int r = 0; r < 4; ++r) sc[r] = __shfl(scale, (lane & 48) + 4 * lg + r);
        #pragma unroll
        for (int t = 0; t < 12; ++t) {
            acc[t][0] *= sc[0]; acc[t][1] *= sc[1];
            acc[t][2] *= sc[2]; acc[t][3] *= sc[3];
        }

        const float* vb = K + ((k0 + lg * 8) * BB + b) * DD + d0 + lr;
        #pragma unroll
        for (int nt = 0; nt < 12; ++nt) {
            const float* vp = vb + nt * 16;
            float vv[8];
            #pragma unroll
            for (int t = 0; t < 8; ++t) vv[t] = vp[t * BB * DD];
            H8 vf;
            vf.u[0] = pk2(vv[0], vv[1]); vf.u[1] = pk2(vv[2], vv[3]);
            vf.u[2] = pk2(vv[4], vv[5]); vf.u[3] = pk2(vv[6], vv[7]);
            acc[nt] = __builtin_amdgcn_mfma_f32_16x16x32_f16(pf.h, vf.h, acc[nt], 0, 0, 0);
        }
    }

    float il[4];
    {
        const float inv = 1.f / (Lrun + 1e-8f);
        #pragma unroll
        for (int r = 0; r < 4; ++r) il[r] = __shfl(inv, (lane & 48) + 4 * lg + r);
    }
    #pragma unroll
    for (int nt = 0; nt < 12; ++nt) {
        #pragma unroll
        for (int r = 0; r < 4; ++r) {
            OUT[((q0 + 4 * lg + r) * BB + b) * DD + d0 + nt * 16 + lr] = acc[nt][r] * il[r];
        }
    }
}

extern "C" void kernel_launch(void* const* d_in, const int* in_sizes, int n_in,
                              void* d_out, int out_size, void* d_ws, size_t ws_size,
                              hipStream_t stream) {
    (void)in_sizes; (void)n_in; (void)out_size;
    const float* x1 = (const float*)d_in[0];
    const float* m1 = (const float*)d_in[1];
    const float* x2 = (const float*)d_in[2];
    const float* m2 = (const float*)d_in[3];
    float* o1 = (float*)d_out;
    float* o2 = o1 + (size_t)LQ * BB * DD;

    const size_t ELEMS = (size_t)LQ * BB * DD;
    const size_t NEED  = 4 * ELEMS * sizeof(_Float16);   // xf1,xf2,xt1,xt2 = 96 MiB

    if (ws_size >= NEED) {
        _Float16* xf1 = (_Float16*)d_ws;
        _Float16* xf2 = xf1 + ELEMS;
        _Float16* xt1 = xf2 + ELEMS;
        _Float16* xt2 = xt1 + ELEMS;
        prep_cvt_t<<<6144, 256, 0, stream>>>(x1, x2, xf1, xf2, xt1, xt2);
        // 2 sides x 32 b x 16 q-tiles (32 rows) = 1024 blocks
        coatt_flash_f16<<<1024, 256, 0, stream>>>(xf1, xf2, xt1, xt2, m1, m2, o1, o2);
    } else {
        coatt_flash_f32<<<2048, 256, 0, stream>>>(x1, m1, x2, m2, o1, o2);
    }
}

// Round 9
// 163.736 us; speedup vs baseline: 1.9861x; 1.9861x over previous
//
#include <hip/hip_runtime.h>

// Problem constants
#define LQ  512
#define LKN 512
#define BB  32
#define DD  768
#define DSL (DD / 4)

typedef float    f4     __attribute__((ext_vector_type(4)));
typedef _Float16 half8  __attribute__((ext_vector_type(8)));
typedef _Float16 half4  __attribute__((ext_vector_type(4)));
typedef __fp16   fp16x2 __attribute__((ext_vector_type(2)));

union H8 { half8 h; unsigned int u[4]; };

__device__ __forceinline__ unsigned int pk2(float a, float b) {
    union { fp16x2 h; unsigned int u; } c;
    c.h = __builtin_amdgcn_cvt_pkrtz(a, b);
    return c.u;
}
__device__ __forceinline__ half8 cvt8(f4 a, f4 b) {
    H8 r;
    r.u[0] = pk2(a[0], a[1]); r.u[1] = pk2(a[2], a[3]);
    r.u[2] = pk2(b[0], b[1]); r.u[3] = pk2(b[2], b[3]);
    return r.h;
}
__device__ __forceinline__ _Float16 u16h(unsigned short s) {
    union { unsigned short u; _Float16 h; } c; c.u = s; return c.h;
}

// ---------------------------------------------------------------------------
// Prep (unchanged): XF fragment-packed f16; XT transposed f16 [B][D][L].
// ---------------------------------------------------------------------------
__global__ __launch_bounds__(256)
void prep_cvt_t(const float* __restrict__ x1, const float* __restrict__ x2,
                _Float16* __restrict__ xf1, _Float16* __restrict__ xf2,
                _Float16* __restrict__ xt1, _Float16* __restrict__ xt2)
{
    const int bi   = blockIdx.x;            // 6144
    const int side = bi / 3072;
    const int rem  = bi % 3072;
    const int b    = rem / 96;
    const int rem2 = rem % 96;
    const int l0   = (rem2 / 12) * 64;
    const int d0   = (rem2 % 12) * 64;

    const float* __restrict__ X  = side ? x2  : x1;
    _Float16* __restrict__    XF = side ? xf2 : xf1;
    _Float16* __restrict__    XT = side ? xt2 : xt1;

    __shared__ _Float16 T[64][72];

    const int tid = threadIdx.x;
    {
        const int r  = tid >> 4;
        const int c4 = (tid & 15) * 4;
        for (int rr = r; rr < 64; rr += 16) {
            const size_t idx = ((size_t)(l0 + rr) * BB + b) * DD + d0 + c4;
            f4 v = *(const f4*)(X + idx);
            half4 h;
            h[0] = (_Float16)v[0]; h[1] = (_Float16)v[1];
            h[2] = (_Float16)v[2]; h[3] = (_Float16)v[3];
            *(half4*)&T[rr][c4] = h;
        }
    }
    __syncthreads();
    {
        const int d  = tid >> 2;
        const int lq = (tid & 3) * 16;
        half8 a, c;
        #pragma unroll
        for (int i = 0; i < 8; ++i) { a[i] = T[lq + i][d]; c[i] = T[lq + 8 + i][d]; }
        _Float16* p = XT + ((size_t)b * DD + d0 + d) * LKN + l0 + lq;
        *(half8*)p       = a;
        *(half8*)(p + 8) = c;
    }
    #pragma unroll
    for (int c = tid; c < 512; c += 256) {
        const int t16l = c >> 7;
        const int ksl  = (c >> 6) & 1;
        const int ln   = c & 63;
        half8 v = *(const half8*)&T[t16l * 16 + (ln & 15)][ksl * 32 + (ln >> 4) * 8];
        const size_t t16g = (size_t)(l0 >> 4) + t16l;
        const size_t ksg  = (size_t)(d0 >> 5) + ksl;
        *(half8*)(XF + (((size_t)b * 32 + t16g) * 24 + ksg) * 512 + ln * 8) = v;
    }
}

// ---------------------------------------------------------------------------
// Stage 1: S = x1.x2^T per b, 128x128 tile per block; writes S[b][l][m] f16
// and ST[b][m][l] f16 (via LDS transpose bounce). 4 waves in 2x2.
// ---------------------------------------------------------------------------
__global__ __launch_bounds__(256, 3)
void gemm_s(const _Float16* __restrict__ xf1, const _Float16* __restrict__ xf2,
            _Float16* __restrict__ S, _Float16* __restrict__ ST)
{
    const int i   = blockIdx.x;            // 512
    const int xcd = i & 7;
    const int j   = i >> 3;                // 0..63
    const int b   = xcd * 4 + (j & 3);
    const int t   = j >> 2;                // 0..15
    const int lt  = t >> 2, mt = t & 3;
    const int l0b = lt * 128, m0b = mt * 128;

    const int tid  = threadIdx.x;
    const int lane = tid & 63;
    const int w    = tid >> 6;
    const int wl   = w >> 1, wm = w & 1;
    const int lr   = lane & 15;
    const int lg   = lane >> 4;

    __shared__ char tr[128 * 264];         // f16[128][132] padded

    f4 acc[16];                            // [i*4+j]
    #pragma unroll
    for (int t2 = 0; t2 < 16; ++t2) acc[t2] = f4{0.f, 0.f, 0.f, 0.f};

    {
        const _Float16* ab = xf1 + (((size_t)b * 32 + lt * 8 + wl * 4) * 24) * 512 + lane * 8;
        const _Float16* bb = xf2 + (((size_t)b * 32 + mt * 8 + wm * 4) * 24) * 512 + lane * 8;
        __builtin_amdgcn_s_setprio(1);
        #pragma unroll
        for (int ks = 0; ks < 24; ++ks) {
            half8 aF[4], bF[4];
            #pragma unroll
            for (int q = 0; q < 4; ++q) {
                aF[q] = *(const half8*)(ab + ((size_t)q * 24 + ks) * 512);
                bF[q] = *(const half8*)(bb + ((size_t)q * 24 + ks) * 512);
            }
            #pragma unroll
            for (int q = 0; q < 4; ++q)
                #pragma unroll
                for (int p = 0; p < 4; ++p)
                    acc[q * 4 + p] = __builtin_amdgcn_mfma_f32_16x16x32_f16(aF[q], bF[p], acc[q * 4 + p], 0, 0, 0);
        }
        __builtin_amdgcn_s_setprio(0);
    }

    // direct S store (f16) + LDS transpose staging
    {
        _Float16* srow = S + ((size_t)b * 512 + l0b + wl * 64) * 512 + m0b + wm * 64;
        #pragma unroll
        for (int q = 0; q < 4; ++q) {
            #pragma unroll
            for (int p = 0; p < 4; ++p) {
                #pragma unroll
                for (int r = 0; r < 4; ++r) {
                    const float v = acc[q * 4 + p][r];
                    const int lrow = q * 16 + 4 * lg + r;      // within 64
                    const int mcol = p * 16 + lr;
                    srow[(size_t)lrow * 512 + mcol] = (_Float16)v;
                    *(_Float16*)(tr + (wl * 64 + lrow) * 264 + (wm * 64 + mcol) * 2) = (_Float16)v;
                }
            }
        }
    }
    __syncthreads();

    // ST rows from transposed LDS: thread -> 2 m-rows (2*m0, 2*m0+1), 32 l's
    {
        const int m0 = tid & 63;
        const int lh = tid >> 6;           // 0..3
        half8 cA[4], cB[4];
        #pragma unroll
        for (int g = 0; g < 4; ++g) {
            #pragma unroll
            for (int e = 0; e < 8; ++e) {
                const int l = lh * 32 + g * 8 + e;
                const unsigned int d = *(const unsigned int*)(tr + l * 264 + m0 * 4);
                cA[g][e] = u16h((unsigned short)(d & 0xffffu));
                cB[g][e] = u16h((unsigned short)(d >> 16));
            }
        }
        _Float16* stb = ST + ((size_t)b * 512 + m0b + 2 * m0) * 512 + l0b + lh * 32;
        #pragma unroll
        for (int g = 0; g < 4; ++g) *(half8*)(stb + g * 8) = cA[g];
        stb += 512;
        #pragma unroll
        for (int g = 0; g < 4; ++g) *(half8*)(stb + g * 8) = cB[g];
    }
}

// ---------------------------------------------------------------------------
// Stage 2: in-place row softmax (masked, normalized). buf rows: [b][row][512].
// side 0: buf=S, mask=m2 ; side 1: buf=ST, mask=m1. One wave per 8 rows.
// ---------------------------------------------------------------------------
__global__ __launch_bounds__(256)
void softmax_rows(_Float16* __restrict__ S, _Float16* __restrict__ ST,
                  const float* __restrict__ m1, const float* __restrict__ m2)
{
    const int bi   = blockIdx.x;           // 1024
    const int side = bi >> 9;
    const int idx  = bi & 511;
    const int b    = idx >> 4;
    const int rt   = idx & 15;

    _Float16* __restrict__ P = side ? ST : S;
    const float* __restrict__ MK = side ? m1 : m2;

    const int tid  = threadIdx.x;
    const int lane = tid & 63;
    const int w    = tid >> 6;

    __shared__ float mask_s[LKN];
    mask_s[tid] = MK[tid * BB + b];
    mask_s[tid + 256] = MK[(tid + 256) * BB + b];
    __syncthreads();

    float mk[8];
    #pragma unroll
    for (int j = 0; j < 8; ++j) mk[j] = mask_s[lane * 8 + j];

    for (int rr = 0; rr < 8; ++rr) {
        const int row = rt * 32 + w * 8 + rr;
        _Float16* rp = P + ((size_t)b * 512 + row) * 512 + lane * 8;
        const half8 v = *(const half8*)rp;
        float f[8];
        #pragma unroll
        for (int j = 0; j < 8; ++j) f[j] = (float)v[j];
        float m = fmaxf(fmaxf(fmaxf(f[0], f[1]), fmaxf(f[2], f[3])),
                        fmaxf(fmaxf(f[4], f[5]), fmaxf(f[6], f[7])));
        #pragma unroll
        for (int d = 1; d <= 32; d <<= 1) m = fmaxf(m, __shfl_xor(m, d));
        float e[8], s = 0.f;
        #pragma unroll
        for (int j = 0; j < 8; ++j) { e[j] = __expf(f[j] - m) * mk[j]; s += e[j]; }
        #pragma unroll
        for (int d = 1; d <= 32; d <<= 1) s += __shfl_xor(s, d);
        const float inv = 1.f / (s + 1e-8f);
        H8 o;
        o.u[0] = pk2(e[0] * inv, e[1] * inv); o.u[1] = pk2(e[2] * inv, e[3] * inv);
        o.u[2] = pk2(e[4] * inv, e[5] * inv); o.u[3] = pk2(e[6] * inv, e[7] * inv);
        *(half8*)rp = o.h;
    }
}

// ---------------------------------------------------------------------------
// Stage 3: OUT = P.V  (side 0: P1=S, V=x2 via xt2, out o1; side 1: P2=ST,
// V=x1 via xt1, out o2). Block: 64 l-rows x 384 d; P-tile staged in LDS once.
// ---------------------------------------------------------------------------
__global__ __launch_bounds__(256, 2)
void pv_gemm(const _Float16* __restrict__ S, const _Float16* __restrict__ ST,
             const _Float16* __restrict__ xt1, const _Float16* __restrict__ xt2,
             float* __restrict__ o1, float* __restrict__ o2)
{
    const int i    = blockIdx.x;           // 1024
    const int xcd  = i & 7;
    const int j    = i >> 3;               // 0..127
    const int b    = xcd * 4 + (j & 3);
    const int rest = j >> 2;               // 0..31
    const int side = rest & 1;
    const int lt   = (rest >> 1) & 7;      // 8 l-tiles of 64
    const int dh   = rest >> 4;            // 0..1
    const int l0   = lt * 64;
    const int dblk = dh * 384;

    const _Float16* __restrict__ P  = side ? ST : S;
    const _Float16* __restrict__ VT = side ? xt1 : xt2;
    float* __restrict__ OUT         = side ? o2 : o1;

    const int tid  = threadIdx.x;
    const int lane = tid & 63;
    const int w    = tid >> 6;
    const int lr   = lane & 15;
    const int lg   = lane >> 4;

    __shared__ char plds[64 * 1024];       // 64 KB, byte = row*1024 + (col2 ^ ((row&7)<<4))

    // stage P-tile (64 rows x 512 cols f16), coalesced, swizzled on LDS write
    {
        const int row = tid & 63;
        const int seg = tid >> 6;          // 0..3
        const _Float16* src = P + ((size_t)b * 512 + l0 + row) * 512 + seg * 128;
        #pragma unroll
        for (int it = 0; it < 16; ++it) {
            const half8 v = *(const half8*)(src + it * 8);
            const int byo = (seg * 256 + it * 16) ^ ((row & 7) << 4);
            *(half8*)(plds + row * 1024 + byo) = v;
        }
    }
    __syncthreads();

    f4 acc[24];                            // [q(l-16tile 0..3)][nt(0..5)]
    #pragma unroll
    for (int t = 0; t < 24; ++t) acc[t] = f4{0.f, 0.f, 0.f, 0.f};

    {
        const _Float16* vtb = VT + ((size_t)b * DD + dblk + w * 96 + lr) * LKN + lg * 8;
        __builtin_amdgcn_s_setprio(1);
        #pragma unroll
        for (int ks2 = 0; ks2 < 16; ++ks2) {
            half8 pa[4];
            #pragma unroll
            for (int q = 0; q < 4; ++q) {
                const int row = q * 16 + lr;
                pa[q] = *(const half8*)(plds + row * 1024 + ((ks2 * 64 + lg * 16) ^ ((row & 7) << 4)));
            }
            #pragma unroll
            for (int nt = 0; nt < 6; ++nt) {
                const half8 vf = *(const half8*)(vtb + (size_t)nt * 16 * LKN + ks2 * 32);
                #pragma unroll
                for (int q = 0; q < 4; ++q)
                    acc[q * 6 + nt] = __builtin_amdgcn_mfma_f32_16x16x32_f16(pa[q], vf, acc[q * 6 + nt], 0, 0, 0);
            }
        }
        __builtin_amdgcn_s_setprio(0);
    }

    #pragma unroll
    for (int q = 0; q < 4; ++q) {
        #pragma unroll
        for (int nt = 0; nt < 6; ++nt) {
            #pragma unroll
            for (int r = 0; r < 4; ++r) {
                OUT[((size_t)(l0 + q * 16 + 4 * lg + r) * BB + b) * DD + dblk + w * 96 + nt * 16 + lr]
                    = acc[q * 6 + nt][r];
            }
        }
    }
}

// ---------------------------------------------------------------------------
// Fallback A (r7 fused kernel, needs 96 MiB ws) — proven path.
// ---------------------------------------------------------------------------
__global__ __launch_bounds__(256, 3)
void coatt_flash_f16(const _Float16* __restrict__ xf1, const _Float16* __restrict__ xf2,
                     const _Float16* __restrict__ xt1, const _Float16* __restrict__ xt2,
                     const float* __restrict__ m1, const float* __restrict__ m2,
                     float* __restrict__ o1, float* __restrict__ o2)
{
    const int i    = blockIdx.x;
    const int xcd  = i & 7;
    const int j    = i >> 3;
    const int pair = xcd * 8 + (j >> 5);
    const int qt   = j & 31;
    const int side = pair >> 5;
    const int b    = pair & 31;

    const _Float16* __restrict__ QF = side ? xf2 : xf1;
    const _Float16* __restrict__ KF = side ? xf1 : xf2;
    const _Float16* __restrict__ VT = side ? xt1 : xt2;
    const float* __restrict__    MK = side ? m1  : m2;
    float* __restrict__         OUT = side ? o2  : o1;

    const int tid  = threadIdx.x;
    const int lane = tid & 63;
    const int w    = tid >> 6;
    const int lr   = lane & 15;
    const int lg   = lane >> 4;
    const int q0 = qt * 16;

    __shared__ _Float16 plds_h[16 * LKN];
    __shared__ float redmax[4][16];
    __shared__ float redsum[4][16];
    __shared__ float mask_s[LKN];
    char* const pb = (char*)plds_h;

    for (int t = tid; t < LKN; t += 256) mask_s[t] = MK[t * BB + b];

    f4 sacc[8];
    #pragma unroll
    for (int t = 0; t < 8; ++t) sacc[t] = f4{0.f, 0.f, 0.f, 0.f};
    {
        const _Float16* qbase = QF + (((size_t)b * 32 + qt) * 24) * 512 + lane * 8;
        const _Float16* kbase = KF + (((size_t)b * 32 + w * 8) * 24) * 512 + lane * 8;
        #pragma unroll
        for (int half = 0; half < 2; ++half) {
            half8 qf[12];
            #pragma unroll
            for (int ks = 0; ks < 12; ++ks) qf[ks] = *(const half8*)(qbase + (half * 12 + ks) * 512);
            __builtin_amdgcn_s_setprio(1);
            #pragma unroll
            for (int ks = 0; ks < 12; ++ks) {
                #pragma unroll
                for (int kt = 0; kt < 8; ++kt) {
                    const half8 kf = *(const half8*)(kbase + ((size_t)kt * 24 + half * 12 + ks) * 512);
                    sacc[kt] = __builtin_amdgcn_mfma_f32_16x16x32_f16(qf[ks], kf, sacc[kt], 0, 0, 0);
                }
            }
            __builtin_amdgcn_s_setprio(0);
        }
    }

    float rm[4];
    #pragma unroll
    for (int r = 0; r < 4; ++r) {
        float m0 = fmaxf(fmaxf(sacc[0][r], sacc[1][r]), fmaxf(sacc[2][r], sacc[3][r]));
        float m1_ = fmaxf(fmaxf(sacc[4][r], sacc[5][r]), fmaxf(sacc[6][r], sacc[7][r]));
        rm[r] = fmaxf(m0, m1_);
    }
    #pragma unroll
    for (int d = 1; d <= 8; d <<= 1) {
        #pragma unroll
        for (int r = 0; r < 4; ++r) rm[r] = fmaxf(rm[r], __shfl_xor(rm[r], d));
    }
    {
        float v = (lr == 0) ? rm[0] : (lr == 1) ? rm[1] : (lr == 2) ? rm[2] : rm[3];
        if (lr < 4) redmax[w][4 * lg + lr] = v;
    }
    __syncthreads();
    float M[4];
    #pragma unroll
    for (int r = 0; r < 4; ++r)
        M[r] = fmaxf(fmaxf(redmax[0][4 * lg + r], redmax[1][4 * lg + r]),
                     fmaxf(redmax[2][4 * lg + r], redmax[3][4 * lg + r]));
    float mval[8];
    #pragma unroll
    for (int kt = 0; kt < 8; ++kt) mval[kt] = mask_s[w * 128 + kt * 16 + lr];
    float ps[4] = {0.f, 0.f, 0.f, 0.f};
    #pragma unroll
    for (int kt = 0; kt < 8; ++kt) {
        #pragma unroll
        for (int r = 0; r < 4; ++r) {
            const float p = __expf(sacc[kt][r] - M[r]) * mval[kt];
            ps[r] += p;
            const int row = 4 * lg + r;
            *(_Float16*)(pb + row * 1024 + (((w * 128 + kt * 16 + lr) * 2) ^ ((row & 7) << 4))) = (_Float16)p;
        }
    }
    #pragma unroll
    for (int d = 1; d <= 8; d <<= 1) {
        #pragma unroll
        for (int r = 0; r < 4; ++r) ps[r] += __shfl_xor(ps[r], d);
    }
    {
        float v = (lr == 0) ? ps[0] : (lr == 1) ? ps[1] : (lr == 2) ? ps[2] : ps[3];
        if (lr < 4) redsum[w][4 * lg + lr] = v;
    }
    __syncthreads();
    float il[4];
    #pragma unroll
    for (int r = 0; r < 4; ++r) {
        const float L = redsum[0][4 * lg + r] + redsum[1][4 * lg + r]
                      + redsum[2][4 * lg + r] + redsum[3][4 * lg + r];
        il[r] = 1.f / (L + 1e-8f);
    }
    const int d0 = w * DSL;
    f4 acc[12];
    #pragma unroll
    for (int t = 0; t < 12; ++t) acc[t] = f4{0.f, 0.f, 0.f, 0.f};
    {
        const _Float16* vtb = VT + ((size_t)b * DD + d0 + lr) * LKN + lg * 8;
        __builtin_amdgcn_s_setprio(1);
        #pragma unroll
        for (int ks2 = 0; ks2 < 16; ++ks2) {
            const half8 pa = *(const half8*)(pb + lr * 1024 + ((ks2 * 64 + lg * 16) ^ ((lr & 7) << 4)));
            #pragma unroll
            for (int nt = 0; nt < 12; ++nt) {
                const half8 vf = *(const half8*)(vtb + (size_t)nt * 16 * LKN + ks2 * 32);
                acc[nt] = __builtin_amdgcn_mfma_f32_16x16x32_f16(pa, vf, acc[nt], 0, 0, 0);
            }
        }
        __builtin_amdgcn_s_setprio(0);
    }
    #pragma unroll
    for (int nt = 0; nt < 12; ++nt) {
        #pragma unroll
        for (int r = 0; r < 4; ++r) {
            OUT[((size_t)(q0 + 4 * lg + r) * BB + b) * DD + d0 + nt * 16 + lr] = acc[nt][r] * il[r];
        }
    }
}

// ---------------------------------------------------------------------------
// Fallback B (f32 direct, no ws).
// ---------------------------------------------------------------------------
__global__ __launch_bounds__(256)
void coatt_flash_f32(const float* __restrict__ x1, const float* __restrict__ m1,
                     const float* __restrict__ x2, const float* __restrict__ m2,
                     float* __restrict__ o1, float* __restrict__ o2)
{
    const int i    = blockIdx.x;
    const int xcd  = i & 7;
    const int j    = i >> 3;
    const int pair = xcd * 8 + (j >> 5);
    const int qt   = j & 31;
    const int side = pair >> 5;
    const int b    = pair & 31;

    const float* __restrict__ Q   = side ? x2 : x1;
    const float* __restrict__ K   = side ? x1 : x2;
    const float* __restrict__ MK  = side ? m1 : m2;
    float* __restrict__       OUT = side ? o2 : o1;

    const int tid  = threadIdx.x;
    const int lane = tid & 63;
    const int w    = tid >> 6;
    const int lr   = lane & 15;
    const int lg   = lane >> 4;
    const int q0 = qt * 16;
    const int d0 = w * DSL;

    __shared__ float sred[4][16][36];
    __shared__ float mask_s[LKN];
    for (int t = tid; t < LKN; t += 256) mask_s[t] = MK[t * BB + b];

    half8 qf[6];
    {
        const float* qrow = Q + ((q0 + lr) * BB + b) * DD + d0 + lg * 8;
        #pragma unroll
        for (int ks = 0; ks < 6; ++ks) {
            f4 a = *(const f4*)(qrow + ks * 32);
            f4 c = *(const f4*)(qrow + ks * 32 + 4);
            qf[ks] = cvt8(a, c);
        }
    }
    f4 acc[12];
    #pragma unroll
    for (int t = 0; t < 12; ++t) acc[t] = f4{0.f, 0.f, 0.f, 0.f};
    float Mrun = -3.0e38f, Lrun = 0.f;
    for (int kt = 0; kt < 16; ++kt) {
        const int k0 = kt * 32;
        f4 s0 = {0.f,0.f,0.f,0.f}, s1 = {0.f,0.f,0.f,0.f};
        {
            const float* kb0 = K + ((k0 + lr) * BB + b) * DD + d0 + lg * 8;
            const float* kb1 = kb0 + 16 * BB * DD;
            #pragma unroll
            for (int ks = 0; ks < 6; ++ks) {
                f4 a0 = *(const f4*)(kb0 + ks * 32);
                f4 c0 = *(const f4*)(kb0 + ks * 32 + 4);
                s0 = __builtin_amdgcn_mfma_f32_16x16x32_f16(qf[ks], cvt8(a0, c0), s0, 0, 0, 0);
                f4 a1 = *(const f4*)(kb1 + ks * 32);
                f4 c1 = *(const f4*)(kb1 + ks * 32 + 4);
                s1 = __builtin_amdgcn_mfma_f32_16x16x32_f16(qf[ks], cvt8(a1, c1), s1, 0, 0, 0);
            }
        }
        __syncthreads();
        #pragma unroll
        for (int r = 0; r < 4; ++r) {
            sred[w][4 * lg + r][lr]      = s0[r];
            sred[w][4 * lg + r][16 + lr] = s1[r];
        }
        __syncthreads();
        f4 sa = {0.f,0.f,0.f,0.f}, sb = {0.f,0.f,0.f,0.f};
        #pragma unroll
        for (int ww = 0; ww < 4; ++ww) {
            sa += *(const f4*)&sred[ww][lr][lg * 8];
            sb += *(const f4*)&sred[ww][lr][lg * 8 + 4];
        }
        float tmax = fmaxf(fmaxf(fmaxf(sa[0], sa[1]), fmaxf(sa[2], sa[3])),
                           fmaxf(fmaxf(sb[0], sb[1]), fmaxf(sb[2], sb[3])));
        tmax = fmaxf(tmax, __shfl_xor(tmax, 16));
        tmax = fmaxf(tmax, __shfl_xor(tmax, 32));
        const float Mnew  = fmaxf(Mrun, tmax);
        const float scale = __expf(Mrun - Mnew);
        float p[8];
        float psum = 0.f;
        const float* mrow = &mask_s[k0 + lg * 8];
        #pragma unroll
        for (int t = 0; t < 4; ++t) { p[t]     = __expf(sa[t] - Mnew) * mrow[t];     psum += p[t]; }
        #pragma unroll
        for (int t = 0; t < 4; ++t) { p[4 + t] = __expf(sb[t] - Mnew) * mrow[4 + t]; psum += p[4 + t]; }
        psum += __shfl_xor(psum, 16);
        psum += __shfl_xor(psum, 32);
        Lrun = Lrun * scale + psum;
        Mrun = Mnew;
        H8 pf;
        pf.u[0] = pk2(p[0], p[1]); pf.u[1] = pk2(p[2], p[3]);
        pf.u[2] = pk2(p[4], p[5]); pf.u[3] = pk2(p[6], p[7]);
        float sc[4];
        #pragma unroll
        for (int r = 0; r < 4; ++r) sc[r] = __shfl(scale, (lane & 48) + 4 * lg + r);
        #pragma unroll
        for (int t = 0; t < 12; ++t) {
            acc[t][0] *= sc[0]; acc[t][1] *= sc[1];
            acc[t][2] *= sc[2]; acc[t][3] *= sc[3];
        }
        const float* vb = K + ((k0 + lg * 8) * BB + b) * DD + d0 + lr;
        #pragma unroll
        for (int nt = 0; nt < 12; ++nt) {
            const float* vp = vb + nt * 16;
            float vv[8];
            #pragma unroll
            for (int t = 0; t < 8; ++t) vv[t] = vp[t * BB * DD];
            H8 vf;
            vf.u[0] = pk2(vv[0], vv[1]); vf.u[1] = pk2(vv[2], vv[3]);
            vf.u[2] = pk2(vv[4], vv[5]); vf.u[3] = pk2(vv[6], vv[7]);
            acc[nt] = __builtin_amdgcn_mfma_f32_16x16x32_f16(pf.h, vf.h, acc[nt], 0, 0, 0);
        }
    }
    float il[4];
    {
        const float inv = 1.f / (Lrun + 1e-8f);
        #pragma unroll
        for (int r = 0; r < 4; ++r) il[r] = __shfl(inv, (lane & 48) + 4 * lg + r);
    }
    #pragma unroll
    for (int nt = 0; nt < 12; ++nt) {
        #pragma unroll
        for (int r = 0; r < 4; ++r) {
            OUT[((q0 + 4 * lg + r) * BB + b) * DD + d0 + nt * 16 + lr] = acc[nt][r] * il[r];
        }
    }
}

extern "C" void kernel_launch(void* const* d_in, const int* in_sizes, int n_in,
                              void* d_out, int out_size, void* d_ws, size_t ws_size,
                              hipStream_t stream) {
    (void)in_sizes; (void)n_in; (void)out_size;
    const float* x1 = (const float*)d_in[0];
    const float* m1 = (const float*)d_in[1];
    const float* x2 = (const float*)d_in[2];
    const float* m2 = (const float*)d_in[3];
    float* o1 = (float*)d_out;
    float* o2 = o1 + (size_t)LQ * BB * DD;

    const size_t ELEMS = (size_t)LQ * BB * DD;           // 12.58M
    const size_t SELEM = (size_t)BB * 512 * 512;         // 8.39M
    const size_t NEED1 = 4 * ELEMS * sizeof(_Float16);   // 96 MiB
    const size_t NEED2 = NEED1 + 2 * SELEM * sizeof(_Float16); // 128 MiB

    if (ws_size >= NEED1) {
        _Float16* xf1 = (_Float16*)d_ws;
        _Float16* xf2 = xf1 + ELEMS;
        _Float16* xt1 = xf2 + ELEMS;
        _Float16* xt2 = xt1 + ELEMS;
        prep_cvt_t<<<6144, 256, 0, stream>>>(x1, x2, xf1, xf2, xt1, xt2);
        if (ws_size >= NEED2) {
            _Float16* S  = xt2 + ELEMS;
            _Float16* ST = S + SELEM;
            gemm_s<<<512, 256, 0, stream>>>(xf1, xf2, S, ST);
            softmax_rows<<<1024, 256, 0, stream>>>(S, ST, m1, m2);
            pv_gemm<<<1024, 256, 0, stream>>>(S, ST, xt1, xt2, o1, o2);
        } else {
            coatt_flash_f16<<<2048, 256, 0, stream>>>(xf1, xf2, xt1, xt2, m1, m2, o1, o2);
        }
    } else {
        coatt_flash_f32<<<2048, 256, 0, stream>>>(x1, m1, x2, m2, o1, o2);
    }
}